// Round 7
// baseline (952.998 us; speedup 1.0000x reference)
//
#include <hip/hip_runtime.h>

// B=1024, T=128, LAT=128, HODE=128, HID=256, OUT=128, NC=2, H=64.
// d_out = xs [128,1024,128] f32 ++ lstm_out [1024,2] f32.
//
// Structure: wf (fuse l2h*h2o) ; ode (per-block RK4 chains) ; xw (Wih.yfin -> float4 i,f,g,o)
//            fused(lstm chain = block 0 wave 0, proj blocks 1..2048) ; fc2.
//
// R5/R6: LSTM as a SINGLE-WAVE barrier-free chain. Lane j owns unit j,
// computes all 4 gate dots with v_dot2_f32_f16 (Whh f16 pairs in 128 VGPRs, f32 acc),
// h broadcast via a 128B LDS write->read inside one wave (in-order, no s_barrier).
// R6 fix: scalar (_Float16) casts instead of cvt_pkrtz (return-type mismatch).

typedef short s16x8 __attribute__((ext_vector_type(8)));
typedef float f32x4 __attribute__((ext_vector_type(4)));
typedef _Float16 f16x2 __attribute__((ext_vector_type(2)));
typedef _Float16 f16x8 __attribute__((ext_vector_type(8)));

#define MFMA16(a, b, c) __builtin_amdgcn_mfma_f32_16x16x32_bf16((a), (b), (c), 0, 0, 0)

// Barrier that waits only on LDS ops (lgkmcnt), NOT vmcnt.
__device__ __forceinline__ void lds_barrier() {
  asm volatile("s_waitcnt lgkmcnt(0)\n\ts_barrier" ::: "memory");
}

__device__ __forceinline__ unsigned short f2bf(float x) {
  union { float f; unsigned u; } v; v.f = x;
  return (unsigned short)((v.u + 0x7FFFu + ((v.u >> 16) & 1u)) >> 16);  // RNE
}

// XOR-swizzled LDS byte offset for a [rows][128] bf16 tile (row stride 256B).
__device__ __forceinline__ int swz(int row, int col2) {
  return row * 256 + (col2 ^ ((row & 7) << 4));
}

__device__ __forceinline__ void gemm_tile(const unsigned char* base,
                                          const int* aOff,
                                          const s16x8* wf0, const s16x8* wf1,
                                          f32x4& a0, f32x4& a1) {
#pragma unroll
  for (int ks = 0; ks < 4; ++ks) {
    s16x8 a = *(const s16x8*)(base + aOff[ks]);
    a0 = MFMA16(a, wf0[ks], a0);
    a1 = MFMA16(a, wf1[ks], a1);
  }
}

// ---------------------------------------------------------------------------
// Kernel 1: Wf[o][k] = sum_h h2o[o][h]*l2h[h][k]; bfused[o] = h2o[o].l2h_b + h2o_b[o]
// ---------------------------------------------------------------------------
__global__ __launch_bounds__(128) void wf_kernel(
    const float* __restrict__ h2o, const float* __restrict__ l2h,
    const float* __restrict__ l2hb, const float* __restrict__ h2ob,
    unsigned short* __restrict__ wfo, float* __restrict__ bfo)
{
  const int o = (int)blockIdx.x, k = (int)threadIdx.x;
  float acc = 0.f;
  for (int h = 0; h < 256; ++h) acc = fmaf(h2o[o * 256 + h], l2h[h * 128 + k], acc);
  wfo[o * 128 + k] = f2bf(acc);
  __shared__ float red[128];
  red[k] = h2o[o * 256 + k] * l2hb[k] + h2o[o * 256 + 128 + k] * l2hb[128 + k];
  __syncthreads();
  for (int s = 64; s > 0; s >>= 1) {
    if (k < s) red[k] += red[k + s];
    __syncthreads();
  }
  if (k == 0) bfo[o] = red[0] + h2ob[o];
}

// ---------------------------------------------------------------------------
// Kernel 2: RK4 ODE integration. 64 blocks x 16 rows, 256 thr (4 waves).
// ---------------------------------------------------------------------------
__global__ __launch_bounds__(256) void ode_kernel(
    const float* __restrict__ init, const float* __restrict__ ts,
    const float* __restrict__ w1, const float* __restrict__ b1,
    const float* __restrict__ w2, const float* __restrict__ b2,
    unsigned short* __restrict__ zbuf, float* __restrict__ yfin)
{
  __shared__ __align__(16) unsigned char sY[4096];  // 16 x 128 bf16, swizzled
  __shared__ __align__(16) unsigned char sH[4096];
  const int tid = (int)threadIdx.x;
  const int w = tid >> 6, lane = tid & 63;
  const int l15 = lane & 15, l4 = lane >> 4;
  const int rowbase = (int)blockIdx.x * 16;
  const int colbase = w * 32;

  s16x8 w1f[2][4], w2f[2][4];
#pragma unroll
  for (int tc = 0; tc < 2; ++tc) {
    const int rj = colbase + 16 * tc + l15;
#pragma unroll
    for (int ks = 0; ks < 4; ++ks) {
      const int kb = ks * 32 + l4 * 8;
      s16x8 va, vb;
#pragma unroll
      for (int t = 0; t < 8; ++t) {
        va[t] = (short)f2bf(w1[rj * 128 + kb + t]);
        vb[t] = (short)f2bf(w2[rj * 128 + kb + t]);
      }
      w1f[tc][ks] = va; w2f[tc][ks] = vb;
    }
  }
  float b1v[2], b2v[2];
#pragma unroll
  for (int tc = 0; tc < 2; ++tc) {
    const int cc = colbase + 16 * tc + l15;
    b1v[tc] = b1[cc]; b2v[tc] = b2[cc];
  }

  int aOff[4];
#pragma unroll
  for (int ks = 0; ks < 4; ++ks) aOff[ks] = swz(l15, (ks * 32 + l4 * 8) * 2);
  int cOff[2][4];
#pragma unroll
  for (int tc = 0; tc < 2; ++tc)
#pragma unroll
    for (int r = 0; r < 4; ++r)
      cOff[tc][r] = swz(l4 * 4 + r, (colbase + 16 * tc + l15) * 2);

  float y0[2][4], yac[2][4];
#pragma unroll
  for (int tc = 0; tc < 2; ++tc)
#pragma unroll
    for (int r = 0; r < 4; ++r)
      y0[tc][r] = init[(rowbase + l4 * 4 + r) * 128 + colbase + 16 * tc + l15];

  {
    const int i = tid * 8;
    const int row = i >> 7, col = i & 127;
    union { unsigned short u[8]; s16x8 v; } p;
#pragma unroll
    for (int t = 0; t < 8; ++t) p.u[t] = f2bf(init[(rowbase + row) * 128 + col + t]);
    *(s16x8*)(sY + swz(row, col * 2)) = p.v;
    *(s16x8*)(zbuf + rowbase * 128 + i) = p.v;
  }
  __syncthreads();

  for (int s = 0; s < 127; ++s) {
    const float dt = ts[s + 1] - ts[s];
    const float c16 = dt * (1.f / 6.f), c13 = dt * (1.f / 3.f), ch = dt * 0.5f;
#pragma unroll
    for (int st = 0; st < 4; ++st) {
      f32x4 acc[2];
      const f32x4 fz = {0.f, 0.f, 0.f, 0.f};
      acc[0] = fz; acc[1] = fz;
      gemm_tile(sY, aOff, w1f[0], w1f[1], acc[0], acc[1]);
#pragma unroll
      for (int tc = 0; tc < 2; ++tc)
#pragma unroll
        for (int r = 0; r < 4; ++r) {
          float v = acc[tc][r] + b1v[tc];
          v = v > 0.f ? v : (__expf(v) - 1.f);  // ELU (alpha=1), cheap exp
          *(unsigned short*)(sH + cOff[tc][r]) = f2bf(v);
        }
      lds_barrier();
      f32x4 kc[2];
      kc[0] = fz; kc[1] = fz;
      gemm_tile(sH, aOff, w2f[0], w2f[1], kc[0], kc[1]);
#pragma unroll
      for (int tc = 0; tc < 2; ++tc)
#pragma unroll
        for (int r = 0; r < 4; ++r) {
          const float kv = kc[tc][r] + b2v[tc];
          float yn;
          if (st == 0)      { yac[tc][r] = fmaf(c16, kv, y0[tc][r]);  yn = fmaf(ch, kv, y0[tc][r]); }
          else if (st == 1) { yac[tc][r] = fmaf(c13, kv, yac[tc][r]); yn = fmaf(ch, kv, y0[tc][r]); }
          else if (st == 2) { yac[tc][r] = fmaf(c13, kv, yac[tc][r]); yn = fmaf(dt, kv, y0[tc][r]); }
          else              { y0[tc][r]  = fmaf(c16, kv, yac[tc][r]); yn = y0[tc][r]; }
          *(unsigned short*)(sY + cOff[tc][r]) = f2bf(yn);
        }
      lds_barrier();
    }
    {
      const int i = tid * 8;
      const int row = i >> 7;
      const s16x8 v = *(const s16x8*)(sY + swz(row, (i & 127) * 2));
      *(s16x8*)(zbuf + (long)(s + 1) * 131072 + rowbase * 128 + i) = v;
    }
  }
#pragma unroll
  for (int tc = 0; tc < 2; ++tc)
#pragma unroll
    for (int r = 0; r < 4; ++r)
      yfin[(rowbase + l4 * 4 + r) * 128 + colbase + 16 * tc + l15] = y0[tc][r];
}

// ---------------------------------------------------------------------------
// Kernel 3: XW4[t][j] = float4(i,f,g,o) pre-activations from Wih.yfin + biases.
// Gate row G = q*64+j  ->  XW4[t*256 + j*4 + q].
// ---------------------------------------------------------------------------
__global__ __launch_bounds__(256) void xw_kernel(
    const float* __restrict__ yfin, const float* __restrict__ wih,
    const float* __restrict__ bih, const float* __restrict__ bhh,
    float* __restrict__ XW4)
{
  const int t = (int)blockIdx.x, g = (int)threadIdx.x;
  const int q = g >> 6, j = g & 63;
  __shared__ __align__(16) float ys[128];
  if (g < 128) ys[g] = yfin[t * 128 + g];
  __syncthreads();
  float a0 = 0.f, a1 = 0.f, a2 = 0.f, a3 = 0.f;
#pragma unroll 8
  for (int k = 0; k < 32; ++k) {
    float4 wv = *(const float4*)(wih + g * 128 + 4 * k);
    float4 yv = *(const float4*)(ys + 4 * k);
    a0 = fmaf(wv.x, yv.x, a0); a1 = fmaf(wv.y, yv.y, a1);
    a2 = fmaf(wv.z, yv.z, a2); a3 = fmaf(wv.w, yv.w, a3);
  }
  XW4[t * 256 + j * 4 + q] = bih[g] + bhh[g] + ((a0 + a1) + (a2 + a3));
}

// ---------------------------------------------------------------------------
// Fused kernel: block 0 wave 0 = single-wave LSTM chain; blocks 1..2048 = proj.
// ---------------------------------------------------------------------------
__device__ __forceinline__ void proj_body(
    const unsigned short* __restrict__ zbuf, const unsigned short* __restrict__ wf,
    const float* __restrict__ bfv_, float* __restrict__ xs)
{
  const int tid = (int)threadIdx.x;
  const int w = tid >> 6, lane = tid & 63;
  const int l15 = lane & 15, l4 = lane >> 4;
  const int colbase = w * 32;
  const long rowbase = (long)(blockIdx.x - 1) * 64;

  s16x8 wff[2][4];
#pragma unroll
  for (int tc = 0; tc < 2; ++tc) {
    const int rj = colbase + 16 * tc + l15;
#pragma unroll
    for (int ks = 0; ks < 4; ++ks)
      wff[tc][ks] = *(const s16x8*)(wf + rj * 128 + ks * 32 + l4 * 8);
  }
  const float bv0 = bfv_[colbase + l15], bv1 = bfv_[colbase + 16 + l15];

  const f32x4 fz = {0.f, 0.f, 0.f, 0.f};
  f32x4 acc[4][2];
#pragma unroll
  for (int rt = 0; rt < 4; ++rt) { acc[rt][0] = fz; acc[rt][1] = fz; }

#pragma unroll
  for (int rt = 0; rt < 4; ++rt) {
    const long rb = rowbase + rt * 16 + l15;
#pragma unroll
    for (int ks = 0; ks < 4; ++ks) {
      const s16x8 a = *(const s16x8*)(zbuf + rb * 128 + ks * 32 + l4 * 8);
      acc[rt][0] = MFMA16(a, wff[0][ks], acc[rt][0]);
      acc[rt][1] = MFMA16(a, wff[1][ks], acc[rt][1]);
    }
  }
#pragma unroll
  for (int rt = 0; rt < 4; ++rt)
#pragma unroll
    for (int r = 0; r < 4; ++r) {
      const long row = rowbase + rt * 16 + l4 * 4 + r;
      xs[row * 128 + colbase + l15]      = acc[rt][0][r] + bv0;
      xs[row * 128 + colbase + 16 + l15] = acc[rt][1][r] + bv1;
    }
}

// Single-wave LSTM: lane j owns hidden unit j. No barriers, no cross-wave traffic.
__device__ __forceinline__ void lstm_body(
    const float* __restrict__ XW4,   // [1024][64] float4 (i,f,g,o)
    const float* __restrict__ whh,   // [256][64] f32
    float* __restrict__ hsT)         // [64][1024]
{
  const int j = (int)threadIdx.x;    // 0..63 (wave 0 only)
  __shared__ __align__(16) _Float16 hbuf[64];

  // Whh rows {j, 64+j, 128+j, 192+j} as f16 pairs: 4 x 32 dwords = 128 VGPR.
  f16x2 wp[4][32];
#pragma unroll
  for (int g = 0; g < 4; ++g) {
    const float* wr = whh + (g * 64 + j) * 64;
#pragma unroll
    for (int k = 0; k < 16; ++k) {
      float4 v = *(const float4*)(wr + 4 * k);
      wp[g][2 * k]     = (f16x2){(_Float16)v.x, (_Float16)v.y};
      wp[g][2 * k + 1] = (f16x2){(_Float16)v.z, (_Float16)v.w};
    }
  }

  hbuf[j] = (_Float16)0.f;
  float c = 0.f;

  const float4* XW4v = (const float4*)XW4;
  float4 xq[4];
#pragma unroll
  for (int i = 0; i < 4; ++i) xq[i] = XW4v[i * 64 + j];

  union HU { f16x8 v8; f16x2 p[4]; };

  for (int tb = 0; tb < 256; ++tb) {
#pragma unroll
    for (int i = 0; i < 4; ++i) {
      const int t = tb * 4 + i;
      const float4 xw = xq[i];
      xq[i] = XW4v[((t + 4) & 1023) * 64 + j];  // prefetch 4 steps ahead

      // broadcast-read full h vector (128B, in-order with last step's write)
      HU hv[8];
#pragma unroll
      for (int r = 0; r < 8; ++r) hv[r].v8 = ((const f16x8*)hbuf)[r];

      float ac[4][4];
#pragma unroll
      for (int g = 0; g < 4; ++g)
#pragma unroll
        for (int a = 0; a < 4; ++a) ac[g][a] = 0.f;
#pragma unroll
      for (int r = 0; r < 8; ++r)
#pragma unroll
        for (int p = 0; p < 4; ++p) {
          const int k = r * 4 + p;
#pragma unroll
          for (int g = 0; g < 4; ++g)
            ac[g][k & 3] = __builtin_amdgcn_fdot2(wp[g][k], hv[r].p[p], ac[g][k & 3], false);
        }
      const float pi = xw.x + ((ac[0][0] + ac[0][1]) + (ac[0][2] + ac[0][3]));
      const float pf = xw.y + ((ac[1][0] + ac[1][1]) + (ac[1][2] + ac[1][3]));
      const float pg = xw.z + ((ac[2][0] + ac[2][1]) + (ac[2][2] + ac[2][3]));
      const float po = xw.w + ((ac[3][0] + ac[3][1]) + (ac[3][2] + ac[3][3]));

      const float ig = __builtin_amdgcn_rcpf(1.f + __expf(-pi));
      const float fg = __builtin_amdgcn_rcpf(1.f + __expf(-pf));
      const float gg = fmaf(2.f, __builtin_amdgcn_rcpf(1.f + __expf(-2.f * pg)), -1.f);
      const float og = __builtin_amdgcn_rcpf(1.f + __expf(-po));

      c = fmaf(fg, c, ig * gg);
      const float h = og * fmaf(2.f, __builtin_amdgcn_rcpf(1.f + __expf(-2.f * c)), -1.f);

      hbuf[j] = (_Float16)h;       // next step's broadcast source
      hsT[j * 1024 + t] = h;       // history (L2 write-combines across t)
    }
  }
}

__global__ __launch_bounds__(256) void proj_lstm_kernel(
    const unsigned short* __restrict__ zbuf, const unsigned short* __restrict__ wf,
    const float* __restrict__ bfv_, float* __restrict__ xs,
    const float* __restrict__ XW4, const float* __restrict__ whh,
    float* __restrict__ hsT)
{
  if (blockIdx.x == 0) {
    if (threadIdx.x < 64) lstm_body(XW4, whh, hsT);
    return;
  }
  proj_body(zbuf, wf, bfv_, xs);
}

// ---------------------------------------------------------------------------
// Kernel 5: lstm_out[t][n] = fc2_w[n] . h_t + fc2_b[n]  (reads hsT [64][1024])
// ---------------------------------------------------------------------------
__global__ __launch_bounds__(256) void fc2_kernel(
    const float* __restrict__ hsT, const float* __restrict__ fw,
    const float* __restrict__ fb, float* __restrict__ lout)
{
  const int idx = (int)blockIdx.x * 256 + (int)threadIdx.x;  // 0..2047
  const int n = idx >> 10, t = idx & 1023;
  float acc = fb[n];
#pragma unroll 8
  for (int j = 0; j < 64; ++j) acc = fmaf(fw[n * 64 + j], hsT[j * 1024 + t], acc);
  lout[t * 2 + n] = acc;
}

// ---------------------------------------------------------------------------
extern "C" void kernel_launch(void* const* d_in, const int* in_sizes, int n_in,
                              void* d_out, int out_size, void* d_ws, size_t ws_size,
                              hipStream_t stream) {
  const float* init  = (const float*)d_in[0];
  const float* ts    = (const float*)d_in[1];
  const float* ode_w1 = (const float*)d_in[2];
  const float* ode_b1 = (const float*)d_in[3];
  const float* ode_w2 = (const float*)d_in[4];
  const float* ode_b2 = (const float*)d_in[5];
  const float* l2h_w = (const float*)d_in[6];
  const float* l2h_b = (const float*)d_in[7];
  const float* h2o_w = (const float*)d_in[8];
  const float* h2o_b = (const float*)d_in[9];
  const float* wih   = (const float*)d_in[10];
  const float* whh   = (const float*)d_in[11];
  const float* bih   = (const float*)d_in[12];
  const float* bhh   = (const float*)d_in[13];
  const float* fc2w  = (const float*)d_in[14];
  const float* fc2b  = (const float*)d_in[15];

  char* ws = (char*)d_ws;
  unsigned short* zbuf  = (unsigned short*)(ws);               // 33,554,432 B
  float* yfin           = (float*)(ws + 33554432);             //    524,288 B
  float* XW4            = (float*)(ws + 34078720);             //  1,048,576 B
  float* hsT            = (float*)(ws + 35127296);             //    262,144 B
  unsigned short* wfbuf = (unsigned short*)(ws + 35389440);    //     32,768 B
  float* bfused         = (float*)(ws + 35422208);             //        512 B

  float* xs   = (float*)d_out;
  float* lout = xs + 16777216;

  wf_kernel<<<128, 128, 0, stream>>>(h2o_w, l2h_w, l2h_b, h2o_b, wfbuf, bfused);
  ode_kernel<<<64, 256, 0, stream>>>(init, ts, ode_w1, ode_b1, ode_w2, ode_b2, zbuf, yfin);
  xw_kernel<<<1024, 256, 0, stream>>>(yfin, wih, bih, bhh, XW4);
  proj_lstm_kernel<<<2049, 256, 0, stream>>>(zbuf, wfbuf, bfused, xs, XW4, whh, hsT);
  fc2_kernel<<<8, 256, 0, stream>>>(hsT, fc2w, fc2b, lout);
}